// Round 9
// baseline (1715.073 us; speedup 1.0000x reference)
//
#include <hip/hip_runtime.h>

#define DEV static __device__ __forceinline__

typedef float f32x4 __attribute__((ext_vector_type(4)));
typedef __bf16 bf16x8 __attribute__((ext_vector_type(8)));
typedef unsigned int u32x4 __attribute__((ext_vector_type(4)));
typedef unsigned int u32x2 __attribute__((ext_vector_type(2)));

#define NNODE 32768
#define NEDGE 393216

DEV unsigned short f2bf(float f) {
    unsigned int u = __builtin_bit_cast(unsigned int, f);
    u += 0x7FFFu + ((u >> 16) & 1u);
    return (unsigned short)(u >> 16);
}
DEV float bf2f(unsigned int b) {
    unsigned int u = b << 16;
    return __builtin_bit_cast(float, u);
}
DEV unsigned int pk2(float a, float b) {
    return (unsigned int)f2bf(a) | ((unsigned int)f2bf(b) << 16);
}
DEV float sigf(float x) { return 1.f / (1.f + __expf(-x)); }

// async global->LDS, 16B per lane; LDS dest = wave-uniform base + lane*16
DEV void gld16(const void* g, void* l) {
    __builtin_amdgcn_global_load_lds(
        (const __attribute__((address_space(1))) void*)(g),
        (__attribute__((address_space(3))) void*)(l),
        16, 0, 0);
}

// ---------------- setup kernels ----------------

__global__ __launch_bounds__(256) void init_k(
    const float* __restrict__ feat,
    unsigned short* __restrict__ hb0, unsigned short* __restrict__ hb1,
    unsigned short* __restrict__ fb)
{
    int idx = blockIdx.x * 256 + threadIdx.x;   // (NNODE+8)*256
    int r = idx >> 8, c = idx & 255;
    float f = 0.f;
    if (r < NNODE && c < 128) f = feat[(size_t)r * 128 + c];
    unsigned short v = f2bf(f);
    hb0[(size_t)r * 256 + c] = v;
    hb1[(size_t)r * 256 + c] = v;
    if (c < 128) fb[(size_t)r * 128 + c] = v;
}

// WT [1024,256]: row j = t*256+o, col d -> Wm[t][d][o]
__global__ __launch_bounds__(256) void prep_wmsg_k(
    const float* __restrict__ Wm, unsigned short* __restrict__ WT)
{
    int idx = blockIdx.x * 256 + threadIdx.x;   // 1024*256
    int j = idx >> 8, d = idx & 255;
    int t = j >> 8, o = j & 255;
    WT[idx] = f2bf(Wm[t * 65536 + d * 256 + o]);
}

// GRU weights gate-interleaved: col' = band*64 + g*16 + ch_low,
// ch = band*16 + ch_low, g in {0:r, 1:z, 2:ig, 3:hg}. K: k<256 -> a, else h.
__global__ __launch_bounds__(256) void prep_gru_k(
    const float* __restrict__ Wi, const float* __restrict__ Wh,
    unsigned short* __restrict__ B2T)
{
    int idx = blockIdx.x * 256 + threadIdx.x;   // 1024*512
    int j = idx >> 9, k = idx & 511;
    int band = j >> 6, g = (j >> 4) & 3, ch = (band << 4) + (j & 15);
    float v = 0.f;
    if (g == 0) v = (k < 256) ? Wi[k * 768 + ch] : Wh[(k - 256) * 768 + ch];
    else if (g == 1) v = (k < 256) ? Wi[k * 768 + 256 + ch] : Wh[(k - 256) * 768 + 256 + ch];
    else if (g == 2) { if (k < 256) v = Wi[k * 768 + 512 + ch]; }
    else { if (k >= 256) v = Wh[(k - 256) * 768 + 512 + ch]; }
    B2T[idx] = f2bf(v);
}

__global__ __launch_bounds__(256) void prep_bias2_k(
    const float* __restrict__ bi, const float* __restrict__ bh,
    float* __restrict__ b2)
{
    int j = blockIdx.x * 256 + threadIdx.x;     // 1024
    int band = j >> 6, g = (j >> 4) & 3, ch = (band << 4) + (j & 15);
    float v;
    if (g == 0) v = bi[ch] + bh[ch];
    else if (g == 1) v = bi[256 + ch] + bh[256 + ch];
    else if (g == 2) v = bi[512 + ch];
    else v = bh[512 + ch];
    b2[j] = v;
}

// pack conv weights: BTY [256][768] (kk=k*256+c), BT2 [256][256],
// BTZ [384][1152] (h chunks then f chunks), BTc2 [384][384]
__global__ __launch_bounds__(256) void prep_conv_k(
    const float* __restrict__ c1w, const float* __restrict__ c2w,
    const float* __restrict__ cc1w, const float* __restrict__ cc2w,
    unsigned short* __restrict__ BTY, unsigned short* __restrict__ BT2,
    unsigned short* __restrict__ BTZ, unsigned short* __restrict__ BTc2)
{
    int idx = blockIdx.x * 256 + threadIdx.x;   // 851968 total
    if (idx < 196608) {                                     // BTY
        int o = idx / 768, kk = idx - o * 768, k = kk >> 8, c = kk & 255;
        BTY[idx] = f2bf(c1w[o * 768 + c * 3 + k]);
    } else if (idx < 262144) {                              // BT2 [o][c]
        int r = idx - 196608, o = r >> 8, c = r & 255;
        BT2[r] = f2bf(c2w[o * 256 + c]);
    } else if (idx < 704512) {                              // BTZ
        int jx = idx - 262144, o = jx / 1152, kk = jx - o * 1152;
        float v;
        if (kk < 768) { int k = kk >> 8, c = kk & 255; v = cc1w[o * 1152 + c * 3 + k]; }
        else { int r = kk - 768, kf = r >> 7, cf = r & 127; v = cc1w[o * 1152 + (256 + cf) * 3 + kf]; }
        BTZ[jx] = f2bf(v);
    } else {                                                // BTc2 [o][c]
        int r = idx - 704512, o = r / 384, c = r - o * 384;
        BTc2[r] = f2bf(cc2w[o * 384 + c]);
    }
}

// ---------------- CSR build ----------------

__global__ __launch_bounds__(256) void count_k(
    const int* __restrict__ dst, int* __restrict__ cnt)
{
    int e = blockIdx.x * 256 + threadIdx.x;
    atomicAdd(&cnt[dst[e]], 1);
}

// hierarchical scan: 32 blocks x 1024 local scan -> 1-wave block-sum scan
// -> 32 blocks offset add
__global__ __launch_bounds__(1024) void scan1_k(
    const int* __restrict__ cnt, int* __restrict__ rp, int* __restrict__ bsum)
{
    __shared__ int buf[1024];
    int b = blockIdx.x, tid = threadIdx.x;
    int n = (b << 10) + tid;
    int v = cnt[n];
    buf[tid] = v;
    __syncthreads();
    for (int off = 1; off < 1024; off <<= 1) {
        int x = (tid >= off) ? buf[tid - off] : 0;
        __syncthreads();
        buf[tid] += x;
        __syncthreads();
    }
    rp[n] = buf[tid] - v;                   // local exclusive
    if (tid == 1023) bsum[b] = buf[1023];   // block total
}

__global__ __launch_bounds__(64) void scan2_k(
    const int* __restrict__ bsum, int* __restrict__ boff, int* __restrict__ rp)
{
    int lane = threadIdx.x;
    int v = (lane < 32) ? bsum[lane] : 0;
    int s = v;
    #pragma unroll
    for (int off = 1; off < 32; off <<= 1) {
        int x = __shfl_up(s, off, 64);
        if (lane >= off) s += x;
    }
    if (lane < 32) boff[lane] = s - v;      // exclusive block offset
    if (lane == 31) rp[NNODE] = s;          // grand total
}

__global__ __launch_bounds__(1024) void scan3_k(
    int* __restrict__ rp, const int* __restrict__ boff)
{
    int b = blockIdx.x, tid = threadIdx.x;
    rp[(b << 10) + tid] += boff[b];
}

__global__ __launch_bounds__(256) void fill_k(
    const int* __restrict__ src, const int* __restrict__ dst,
    const int* __restrict__ et, const int* __restrict__ rp,
    int* __restrict__ pos, int* __restrict__ edat)
{
    int e = blockIdx.x * 256 + threadIdx.x;
    int d = dst[e];
    int p = atomicAdd(&pos[d], 1);
    edat[rp[d] + p] = src[e] | (et[e] << 20);
}

// ---------------- per-step kernels ----------------

// one wave per node: gather Hmsg[src, et*256 .. +256] rows, sum fp32 -> Aonly
// unrolled x8 so 8 gathers are in flight
__global__ __launch_bounds__(256) void agg2_k(
    const int* __restrict__ rp, const int* __restrict__ edat,
    const unsigned short* __restrict__ Hmsg, unsigned short* __restrict__ Aonly)
{
    int wave = threadIdx.x >> 6, lane = threadIdx.x & 63;
    int n = (blockIdx.x << 2) + wave;
    int e0 = rp[n], e1 = rp[n + 1];
    float a0 = 0.f, a1 = 0.f, a2 = 0.f, a3 = 0.f;
    const unsigned short* hc = Hmsg + (lane << 2);
    int e = e0;
    for (; e + 8 <= e1; e += 8) {
        u32x2 v[8];
        #pragma unroll
        for (int q = 0; q < 8; q++) {
            int d = edat[e + q];
            v[q] = *(const u32x2*)(hc + ((size_t)(d & 0xFFFFF) << 10) + ((d >> 20) << 8));
        }
        #pragma unroll
        for (int q = 0; q < 8; q++) {
            a0 += bf2f(v[q].x & 0xFFFFu); a1 += bf2f(v[q].x >> 16);
            a2 += bf2f(v[q].y & 0xFFFFu); a3 += bf2f(v[q].y >> 16);
        }
    }
    for (; e < e1; e++) {
        int d = edat[e];
        u32x2 v = *(const u32x2*)(hc + ((size_t)(d & 0xFFFFF) << 10) + ((d >> 20) << 8));
        a0 += bf2f(v.x & 0xFFFFu); a1 += bf2f(v.x >> 16);
        a2 += bf2f(v.y & 0xFFFFu); a3 += bf2f(v.y >> 16);
    }
    u32x2 p; p.x = pk2(a0, a1); p.y = pk2(a2, a3);
    *(u32x2*)(Aonly + (size_t)n * 256 + (lane << 2)) = p;
}

// ---- A-only BK=64 staging: tile stored as two stacked 32-K halves so
// global_load_lds lane-contiguity holds. Thread issues 4 gld16.
#define STAGE_COORDS                                            \
    int srow[4], scb[4], soff[4];                               \
    _Pragma("unroll")                                           \
    for (int p = 0; p < 4; p++) {                               \
        int c = wave + p * 4;                                   \
        int half = c >> 3, cc = c & 7;                          \
        srow[p] = cc * 16 + (lane >> 2);                        \
        scb[p] = ((lane & 3) + half * 4) * 8;                   \
        soff[p] = half * 4096 + cc * 512;                       \
    }

// MFMA over one 64-K tile: A frags from LDS, B frags direct from regs
#define MFMA64_BD(AS, BREG)                                                   \
    _Pragma("unroll")                                                         \
    for (int h = 0; h < 2; h++) {                                             \
        bf16x8 af[4];                                                         \
        _Pragma("unroll")                                                     \
        for (int i = 0; i < 4; i++)                                           \
            af[i] = *(const bf16x8*)(&AS[h * 4096 + (qm + i * 16 + fm) * 32 + fkv * 8]); \
        _Pragma("unroll")                                                     \
        for (int i = 0; i < 4; i++)                                           \
            _Pragma("unroll")                                                 \
            for (int j = 0; j < 4; j++)                                       \
                acc[i][j] = __builtin_amdgcn_mfma_f32_16x16x32_bf16(BREG[h][j], af[i], acc[i][j], 0, 0, 0); \
    }

// bf16 GEMM, B pre-transposed [N,K]; 128x128 tile, BK=64, 4 waves.
// A staged via global_load_lds; B fragments loaded DIRECTLY global->VGPR
// (contiguous 16B per frag, L1/L2-resident weights, no barrier dependency).
// Swapped MFMA: lane holds 4 consecutive N elems -> 8B packed stores.
__global__ __launch_bounds__(256) void gemm_bt(
    const unsigned short* __restrict__ A, int lda,
    const unsigned short* __restrict__ Bt,
    unsigned short* __restrict__ Cb, int ldcb,
    const float* __restrict__ bias,
    int N, int K, int swz, int relu)
{
    __shared__ __align__(16) unsigned short As[128 * 64];
    const int tid = threadIdx.x;
    int id = blockIdx.x;
    if (swz) { int per = gridDim.x >> 3; id = (id & 7) * per + (id >> 3); }
    const int nb = N >> 7;
    const int bm = id / nb, bn = id - bm * nb;
    const int wave = tid >> 6, lane = tid & 63;
    const unsigned short* Ag = A + (size_t)(bm * 128) * lda;
    const int qm = (wave & 1) << 6, qn = (wave >> 1) << 6;
    const int fm = lane & 15, fkv = lane >> 4;
    const unsigned short* Bf = Bt + (size_t)(bn * 128 + qn + fm) * K + fkv * 8;
    STAGE_COORDS

    f32x4 acc[4][4] = {};

    for (int kb = 0; kb < K; kb += 64) {
        bf16x8 breg[2][4];
        #pragma unroll
        for (int h = 0; h < 2; h++)
            #pragma unroll
            for (int j = 0; j < 4; j++)
                breg[h][j] = *(const bf16x8*)(Bf + (size_t)j * 16 * K + kb + h * 32);
        __syncthreads();
        #pragma unroll
        for (int p = 0; p < 4; p++)
            gld16(Ag + (size_t)srow[p] * lda + kb + scb[p], As + soff[p]);
        __syncthreads();
        MFMA64_BD(As, breg)
    }

    const int m0 = bm * 128 + qm + fm;
    const int n0 = bn * 128 + qn + (fkv << 2);
    #pragma unroll
    for (int i = 0; i < 4; i++) {
        int row = m0 + i * 16;
        #pragma unroll
        for (int j = 0; j < 4; j++) {
            int col = n0 + j * 16;
            float v0 = acc[i][j][0], v1 = acc[i][j][1],
                  v2 = acc[i][j][2], v3 = acc[i][j][3];
            if (bias) {
                float4 bv = *(const float4*)(bias + col);
                v0 += bv.x; v1 += bv.y; v2 += bv.z; v3 += bv.w;
            }
            if (relu) {
                v0 = fmaxf(v0, 0.f); v1 = fmaxf(v1, 0.f);
                v2 = fmaxf(v2, 0.f); v3 = fmaxf(v3, 0.f);
            }
            u32x2 p; p.x = pk2(v0, v1); p.y = pk2(v2, v3);
            *(u32x2*)(Cb + (size_t)row * ldcb + col) = p;
        }
    }
}

// conv1 as single K-extended GEMM: C[l,:] = relu(sum_k A[l+k,:] @ Wk + b)
// K layout: kb<768 -> h chunks (lda 256, shift kb>>8), kb>=768 -> f chunks
// (lda 128, shift (kb-768)>>7). B direct-loaded.
__global__ __launch_bounds__(256) void gemm_conv(
    const unsigned short* __restrict__ Ah,
    const unsigned short* __restrict__ Af,
    const unsigned short* __restrict__ Bt,
    unsigned short* __restrict__ Cb, int ldcb,
    const float* __restrict__ bias,
    int N, int K)
{
    __shared__ __align__(16) unsigned short As[128 * 64];
    const int tid = threadIdx.x;
    int id = blockIdx.x;
    { int per = gridDim.x >> 3; id = (id & 7) * per + (id >> 3); }
    const int nb = N >> 7;
    const int bm = id / nb, bn = id - bm * nb;
    const int wave = tid >> 6, lane = tid & 63;
    const int qm = (wave & 1) << 6, qn = (wave >> 1) << 6;
    const int fm = lane & 15, fkv = lane >> 4;
    const unsigned short* Bf = Bt + (size_t)(bn * 128 + qn + fm) * K + fkv * 8;
    STAGE_COORDS

    f32x4 acc[4][4] = {};

    for (int kb = 0; kb < K; kb += 64) {
        bf16x8 breg[2][4];
        #pragma unroll
        for (int h = 0; h < 2; h++)
            #pragma unroll
            for (int j = 0; j < 4; j++)
                breg[h][j] = *(const bf16x8*)(Bf + (size_t)j * 16 * K + kb + h * 32);
        const unsigned short* base; int ldA, col, shift;
        if (kb < 768) { base = Ah; ldA = 256; shift = kb >> 8; col = kb & 255; }
        else { int r = kb - 768; base = Af; ldA = 128; shift = r >> 7; col = r & 127; }
        const unsigned short* Ag = base + (size_t)(bm * 128 + shift) * ldA + col;
        __syncthreads();
        #pragma unroll
        for (int p = 0; p < 4; p++)
            gld16(Ag + (size_t)srow[p] * ldA + scb[p], As + soff[p]);
        __syncthreads();
        MFMA64_BD(As, breg)
    }

    const int m0 = bm * 128 + qm + fm;
    const int n0 = bn * 128 + qn + (fkv << 2);
    #pragma unroll
    for (int i = 0; i < 4; i++) {
        int row = m0 + i * 16;
        #pragma unroll
        for (int j = 0; j < 4; j++) {
            int col = n0 + j * 16;
            float4 bv = *(const float4*)(bias + col);
            float v0 = fmaxf(acc[i][j][0] + bv.x, 0.f);
            float v1 = fmaxf(acc[i][j][1] + bv.y, 0.f);
            float v2 = fmaxf(acc[i][j][2] + bv.z, 0.f);
            float v3 = fmaxf(acc[i][j][3] + bv.w, 0.f);
            u32x2 p; p.x = pk2(v0, v1); p.y = pk2(v2, v3);
            *(u32x2*)(Cb + (size_t)row * ldcb + col) = p;
        }
    }
}

// GRU GEMM + fused gate epilogue (swapped MFMA, BK=64, B direct-loaded).
// A = [a|h] from Aonly / hbc (both [Nn,256] bf16); Bt [1024,512]
// gate-interleaved. gate g = j-frag, channel = band*16 + fkv*4 + r.
__global__ __launch_bounds__(256) void gemm_gru(
    const unsigned short* __restrict__ Aonly,
    const unsigned short* __restrict__ hbc,
    const unsigned short* __restrict__ Bt,
    const float* __restrict__ b2p,
    unsigned short* __restrict__ hbn)
{
    __shared__ __align__(16) unsigned short As[128 * 64];
    const int tid = threadIdx.x;
    int id = blockIdx.x;                        // 2048
    { int per = gridDim.x >> 3; id = (id & 7) * per + (id >> 3); }
    const int bm = id >> 3;
    const int bn = id & 7;
    const int wave = tid >> 6, lane = tid & 63;
    const int qm = (wave & 1) << 6, qn = (wave >> 1) << 6;
    const int fm = lane & 15, fkv = lane >> 4;
    const unsigned short* Bf = Bt + (size_t)(bn * 128 + qn + fm) * 512 + fkv * 8;
    STAGE_COORDS

    f32x4 acc[4][4] = {};

    for (int kb = 0; kb < 512; kb += 64) {
        bf16x8 breg[2][4];
        #pragma unroll
        for (int h = 0; h < 2; h++)
            #pragma unroll
            for (int j = 0; j < 4; j++)
                breg[h][j] = *(const bf16x8*)(Bf + (size_t)j * 16 * 512 + kb + h * 32);
        const unsigned short* base = (kb < 256) ? Aonly : hbc;
        const unsigned short* Ag = base + (size_t)(bm * 128) * 256 + (kb & 255);
        __syncthreads();
        #pragma unroll
        for (int p = 0; p < 4; p++)
            gld16(Ag + (size_t)srow[p] * 256 + scb[p], As + soff[p]);
        __syncthreads();
        MFMA64_BD(As, breg)
    }

    // fused GRU gate epilogue (bf16 state, 8B vector I/O)
    const int band = (bn << 1) + (qn >> 6);
    const int chb = (band << 4) + (fkv << 2);
    const float4 brv = *(const float4*)(b2p + (band << 6) + 0  + (fkv << 2));
    const float4 bzv = *(const float4*)(b2p + (band << 6) + 16 + (fkv << 2));
    const float4 bgv = *(const float4*)(b2p + (band << 6) + 32 + (fkv << 2));
    const float4 bhv = *(const float4*)(b2p + (band << 6) + 48 + (fkv << 2));
    const float br_[4] = {brv.x, brv.y, brv.z, brv.w};
    const float bz_[4] = {bzv.x, bzv.y, bzv.z, bzv.w};
    const float bg_[4] = {bgv.x, bgv.y, bgv.z, bgv.w};
    const float bh_[4] = {bhv.x, bhv.y, bhv.z, bhv.w};
    const int m0 = bm * 128 + qm + fm;
    #pragma unroll
    for (int i = 0; i < 4; i++) {
        int row = m0 + i * 16;
        u32x2 hv = *(const u32x2*)(hbc + (size_t)row * 256 + chb);
        float hp[4] = {bf2f(hv.x & 0xFFFFu), bf2f(hv.x >> 16),
                       bf2f(hv.y & 0xFFFFu), bf2f(hv.y >> 16)};
        float hn[4];
        #pragma unroll
        for (int r = 0; r < 4; r++) {
            float rg = sigf(acc[i][0][r] + br_[r]);
            float zz = sigf(acc[i][1][r] + bz_[r]);
            float pre = acc[i][2][r] + bg_[r] + rg * (acc[i][3][r] + bh_[r]);
            pre = fminf(fmaxf(pre, -15.f), 15.f);
            float t = __expf(2.f * pre);
            float gq = (t - 1.f) / (t + 1.f);
            hn[r] = (1.f - zz) * gq + zz * hp[r];
        }
        u32x2 p; p.x = pk2(hn[0], hn[1]); p.y = pk2(hn[2], hn[3]);
        *(u32x2*)(hbn + (size_t)row * 256 + chb) = p;
    }
}

// maxpool over l (window 3, stride 2), bf16 input (relu pre-applied)
__global__ __launch_bounds__(256) void pool_k(
    const unsigned short* __restrict__ in, int ldin, int Lb_in, int L_out,
    int win, int C,
    unsigned short* __restrict__ ob, int ldo)
{
    int idx = blockIdx.x * 256 + threadIdx.x;
    int c = idx % C;
    int row = idx / C;
    int b = row / L_out, lp = row - b * L_out;
    const unsigned short* p = in + (size_t)(b * Lb_in + 2 * lp) * ldin + c;
    float m = bf2f(p[0]);
    for (int d = 1; d < win; d++) m = fmaxf(m, bf2f(p[(size_t)d * ldin]));
    ob[(size_t)row * ldo + c] = f2bf(m);
}

// fused pool2(win=2) + dot + mean + sigmoid.
// CY [128*126,256] bf16 (relu'd conv2-Y out), CZ [128*126,384] bf16
__global__ __launch_bounds__(64) void final_k(
    const unsigned short* __restrict__ CY, const unsigned short* __restrict__ CZ,
    const float* __restrict__ wy, const float* __restrict__ by,
    const float* __restrict__ wz, const float* __restrict__ bz,
    float* __restrict__ out)
{
    int b = blockIdx.x, lane = threadIdx.x;
    float val = 0.f;
    if (lane < 63) {
        const unsigned short* y0 = CY + (size_t)(b * 126 + 2 * lane) * 256;
        const unsigned short* y1 = y0 + 256;
        float y = 0.f;
        for (int o = 0; o < 256; o++)
            y += fmaxf(bf2f(y0[o]), bf2f(y1[o])) * wy[o];
        y += by[0];
        const unsigned short* z0 = CZ + (size_t)(b * 126 + 2 * lane) * 384;
        const unsigned short* z1 = z0 + 384;
        float z = 0.f;
        for (int o = 0; o < 384; o++)
            z += fmaxf(bf2f(z0[o]), bf2f(z1[o])) * wz[o];
        z += bz[0];
        val = y * z;
    }
    for (int off = 32; off > 0; off >>= 1) val += __shfl_down(val, off, 64);
    if (lane == 0) out[b] = sigf(val * (1.f / 63.f));
}

// ---------------- launch ----------------

extern "C" void kernel_launch(void* const* d_in, const int* in_sizes, int n_in,
                              void* d_out, int out_size, void* d_ws, size_t ws_size,
                              hipStream_t stream)
{
    const float* feat = (const float*)d_in[0];
    const int* src = (const int*)d_in[1];
    const int* dst = (const int*)d_in[2];
    const int* et  = (const int*)d_in[3];
    const float* Wm  = (const float*)d_in[4];
    const float* bm  = (const float*)d_in[5];
    const float* Wi  = (const float*)d_in[6];
    const float* Wh  = (const float*)d_in[7];
    const float* bi  = (const float*)d_in[8];
    const float* bh  = (const float*)d_in[9];
    const float* c1w = (const float*)d_in[10];
    const float* c1b = (const float*)d_in[11];
    const float* c2w = (const float*)d_in[12];
    const float* c2b = (const float*)d_in[13];
    const float* cc1w = (const float*)d_in[14];
    const float* cc1b = (const float*)d_in[15];
    const float* cc2w = (const float*)d_in[16];
    const float* cc2b = (const float*)d_in[17];
    const float* wy = (const float*)d_in[18];
    const float* by = (const float*)d_in[19];
    const float* wz = (const float*)d_in[20];
    const float* bz = (const float*)d_in[21];
    float* out = (float*)d_out;

    char* w = (char*)d_ws;
    size_t off = 0;
    auto alloc = [&](size_t bytes) -> char* {
        char* p = w + off; off += (bytes + 255) & ~(size_t)255; return p;
    };
    unsigned short* hb0 = (unsigned short*)alloc((size_t)(NNODE + 8) * 256 * 2);
    unsigned short* hb1 = (unsigned short*)alloc((size_t)(NNODE + 8) * 256 * 2);
    unsigned short* fb  = (unsigned short*)alloc((size_t)(NNODE + 8) * 128 * 2);
    unsigned short* Aonly = (unsigned short*)alloc((size_t)NNODE * 256 * 2);
    char* R = alloc((size_t)NNODE * 1024 * 2);          // Hmsg / conv1-out overlay
    unsigned short* Hmsg = (unsigned short*)R;          // [Nn,1024] bf16
    unsigned short* CbY  = (unsigned short*)R;          // [Nn,256] bf16 (conv1 Y)
    unsigned short* CbZ  = (unsigned short*)(R + (size_t)NNODE * 256 * 2); // [Nn,384]
    unsigned short* P    = (unsigned short*)alloc((size_t)16128 * 384 * 2);
    unsigned short* Cb2Y = (unsigned short*)alloc((size_t)16128 * 256 * 2);
    unsigned short* Cb2Z = (unsigned short*)alloc((size_t)16128 * 384 * 2);
    unsigned short* WT   = (unsigned short*)alloc(1024 * 256 * 2);
    unsigned short* B2T  = (unsigned short*)alloc(1024 * 512 * 2);
    float* b2            = (float*)alloc(1024 * 4);
    unsigned short* BTY  = (unsigned short*)alloc(256 * 768 * 2);
    unsigned short* BT2  = (unsigned short*)alloc(256 * 256 * 2);
    unsigned short* BTZ  = (unsigned short*)alloc(384 * 1152 * 2);
    unsigned short* BTc2 = (unsigned short*)alloc(384 * 384 * 2);
    int* rp     = (int*)alloc((NNODE + 1) * 4);
    int* pos    = (int*)alloc(NNODE * 4);
    int* cnt    = (int*)alloc(NNODE * 4);
    int* bsum   = (int*)alloc(32 * 4);
    int* boff   = (int*)alloc(32 * 4);
    int* edat   = (int*)alloc(NEDGE * 4);

    // setup
    hipLaunchKernelGGL(init_k, dim3(NNODE + 8), dim3(256), 0, stream, feat, hb0, hb1, fb);
    hipLaunchKernelGGL(prep_wmsg_k, dim3(1024), dim3(256), 0, stream, Wm, WT);
    hipLaunchKernelGGL(prep_gru_k, dim3(2048), dim3(256), 0, stream, Wi, Wh, B2T);
    hipLaunchKernelGGL(prep_bias2_k, dim3(4), dim3(256), 0, stream, bi, bh, b2);
    hipLaunchKernelGGL(prep_conv_k, dim3(3328), dim3(256), 0, stream,
                       c1w, c2w, cc1w, cc2w, BTY, BT2, BTZ, BTc2);
    hipMemsetAsync(pos, 0, NNODE * 4, stream);
    hipMemsetAsync(cnt, 0, NNODE * 4, stream);
    hipLaunchKernelGGL(count_k, dim3(NEDGE / 256), dim3(256), 0, stream, dst, cnt);
    hipLaunchKernelGGL(scan1_k, dim3(32), dim3(1024), 0, stream, cnt, rp, bsum);
    hipLaunchKernelGGL(scan2_k, dim3(1), dim3(64), 0, stream, bsum, boff, rp);
    hipLaunchKernelGGL(scan3_k, dim3(32), dim3(1024), 0, stream, rp, boff);
    hipLaunchKernelGGL(fill_k, dim3(NEDGE / 256), dim3(256), 0, stream, src, dst, et, rp, pos, edat);

    // 8 GGNN steps; bf16 state double-buffered (hb0 -> hb1 -> hb0 ...)
    // per step: Hmsg = hb@WT + bm  ->  Aonly[dst] = sum Hmsg[src, et]  ->  GRU
    unsigned short* hbuf[2] = {hb0, hb1};
    for (int step = 0; step < 8; step++) {
        unsigned short* cur = hbuf[step & 1];
        unsigned short* nxt = hbuf[(step + 1) & 1];
        hipLaunchKernelGGL(gemm_bt, dim3(2048), dim3(256), 0, stream,
            cur, 256, WT, Hmsg, 1024, bm, 1024, 256, 1, 0);
        hipLaunchKernelGGL(agg2_k, dim3(NNODE / 4), dim3(256), 0, stream, rp, edat, Hmsg, Aonly);
        hipLaunchKernelGGL(gemm_gru, dim3(2048), dim3(256), 0, stream,
            Aonly, cur, B2T, b2, nxt);
    }
    // final state is in hb0 (after 8 flips)

    // readout: Y path (relu fused in GEMMs, bf16 intermediates)
    hipLaunchKernelGGL(gemm_conv, dim3(512), dim3(256), 0, stream,
        hb0, (const unsigned short*)nullptr, BTY, CbY, 256, c1b, 256, 768);
    hipLaunchKernelGGL(pool_k, dim3(16128), dim3(256), 0, stream,
        CbY, 256, 256, 126, 3, 256, P, 256);
    hipLaunchKernelGGL(gemm_bt, dim3(252), dim3(256), 0, stream,
        P, 256, BT2, Cb2Y, 256, c2b, 256, 256, 0, 1);

    // Z path
    hipLaunchKernelGGL(gemm_conv, dim3(768), dim3(256), 0, stream,
        hb0, fb, BTZ, CbZ, 384, cc1b, 384, 1152);
    hipLaunchKernelGGL(pool_k, dim3(24192), dim3(256), 0, stream,
        CbZ, 384, 256, 126, 3, 384, P, 384);
    hipLaunchKernelGGL(gemm_bt, dim3(378), dim3(256), 0, stream,
        P, 384, BTc2, Cb2Z, 384, cc2b, 384, 384, 0, 1);

    // fused pool2 + readout heads
    hipLaunchKernelGGL(final_k, dim3(128), dim3(64), 0, stream,
        Cb2Y, Cb2Z, wy, by, wz, bz, out);
}

// Round 10
// 1336.629 us; speedup vs baseline: 1.2831x; 1.2831x over previous
//
#include <hip/hip_runtime.h>

#define DEV static __device__ __forceinline__

typedef float f32x4 __attribute__((ext_vector_type(4)));
typedef __bf16 bf16x8 __attribute__((ext_vector_type(8)));
typedef unsigned int u32x4 __attribute__((ext_vector_type(4)));
typedef unsigned int u32x2 __attribute__((ext_vector_type(2)));

#define NNODE 32768
#define NEDGE 393216

DEV unsigned short f2bf(float f) {
    unsigned int u = __builtin_bit_cast(unsigned int, f);
    u += 0x7FFFu + ((u >> 16) & 1u);
    return (unsigned short)(u >> 16);
}
DEV float bf2f(unsigned int b) {
    unsigned int u = b << 16;
    return __builtin_bit_cast(float, u);
}
DEV unsigned int pk2(float a, float b) {
    return (unsigned int)f2bf(a) | ((unsigned int)f2bf(b) << 16);
}
DEV float sigf(float x) { return 1.f / (1.f + __expf(-x)); }

// async global->LDS, 16B per lane; LDS dest = wave-uniform base + lane*16
DEV void gld16(const void* g, void* l) {
    __builtin_amdgcn_global_load_lds(
        (const __attribute__((address_space(1))) void*)(g),
        (__attribute__((address_space(3))) void*)(l),
        16, 0, 0);
}

// ---------------- setup kernels ----------------

__global__ __launch_bounds__(256) void init_k(
    const float* __restrict__ feat,
    unsigned short* __restrict__ hb0, unsigned short* __restrict__ hb1,
    unsigned short* __restrict__ fb)
{
    int idx = blockIdx.x * 256 + threadIdx.x;   // (NNODE+8)*256
    int r = idx >> 8, c = idx & 255;
    float f = 0.f;
    if (r < NNODE && c < 128) f = feat[(size_t)r * 128 + c];
    unsigned short v = f2bf(f);
    hb0[(size_t)r * 256 + c] = v;
    hb1[(size_t)r * 256 + c] = v;
    if (c < 128) fb[(size_t)r * 128 + c] = v;
}

// WT [1024,256]: row j = t*256+o, col d -> Wm[t][d][o]
__global__ __launch_bounds__(256) void prep_wmsg_k(
    const float* __restrict__ Wm, unsigned short* __restrict__ WT)
{
    int idx = blockIdx.x * 256 + threadIdx.x;   // 1024*256
    int j = idx >> 8, d = idx & 255;
    int t = j >> 8, o = j & 255;
    WT[idx] = f2bf(Wm[t * 65536 + d * 256 + o]);
}

// GRU weights gate-interleaved: col' = band*64 + g*16 + ch_low,
// ch = band*16 + ch_low, g in {0:r, 1:z, 2:ig, 3:hg}. K: k<256 -> a, else h.
__global__ __launch_bounds__(256) void prep_gru_k(
    const float* __restrict__ Wi, const float* __restrict__ Wh,
    unsigned short* __restrict__ B2T)
{
    int idx = blockIdx.x * 256 + threadIdx.x;   // 1024*512
    int j = idx >> 9, k = idx & 511;
    int band = j >> 6, g = (j >> 4) & 3, ch = (band << 4) + (j & 15);
    float v = 0.f;
    if (g == 0) v = (k < 256) ? Wi[k * 768 + ch] : Wh[(k - 256) * 768 + ch];
    else if (g == 1) v = (k < 256) ? Wi[k * 768 + 256 + ch] : Wh[(k - 256) * 768 + 256 + ch];
    else if (g == 2) { if (k < 256) v = Wi[k * 768 + 512 + ch]; }
    else { if (k >= 256) v = Wh[(k - 256) * 768 + 512 + ch]; }
    B2T[idx] = f2bf(v);
}

__global__ __launch_bounds__(256) void prep_bias2_k(
    const float* __restrict__ bi, const float* __restrict__ bh,
    float* __restrict__ b2)
{
    int j = blockIdx.x * 256 + threadIdx.x;     // 1024
    int band = j >> 6, g = (j >> 4) & 3, ch = (band << 4) + (j & 15);
    float v;
    if (g == 0) v = bi[ch] + bh[ch];
    else if (g == 1) v = bi[256 + ch] + bh[256 + ch];
    else if (g == 2) v = bi[512 + ch];
    else v = bh[512 + ch];
    b2[j] = v;
}

// pack conv weights: BTY [256][768] (kk=k*256+c), BT2 [256][256],
// BTZ [384][1152] (h chunks then f chunks), BTc2 [384][384]
__global__ __launch_bounds__(256) void prep_conv_k(
    const float* __restrict__ c1w, const float* __restrict__ c2w,
    const float* __restrict__ cc1w, const float* __restrict__ cc2w,
    unsigned short* __restrict__ BTY, unsigned short* __restrict__ BT2,
    unsigned short* __restrict__ BTZ, unsigned short* __restrict__ BTc2)
{
    int idx = blockIdx.x * 256 + threadIdx.x;   // 851968 total
    if (idx < 196608) {                                     // BTY
        int o = idx / 768, kk = idx - o * 768, k = kk >> 8, c = kk & 255;
        BTY[idx] = f2bf(c1w[o * 768 + c * 3 + k]);
    } else if (idx < 262144) {                              // BT2 [o][c]
        int r = idx - 196608, o = r >> 8, c = r & 255;
        BT2[r] = f2bf(c2w[o * 256 + c]);
    } else if (idx < 704512) {                              // BTZ
        int jx = idx - 262144, o = jx / 1152, kk = jx - o * 1152;
        float v;
        if (kk < 768) { int k = kk >> 8, c = kk & 255; v = cc1w[o * 1152 + c * 3 + k]; }
        else { int r = kk - 768, kf = r >> 7, cf = r & 127; v = cc1w[o * 1152 + (256 + cf) * 3 + kf]; }
        BTZ[jx] = f2bf(v);
    } else {                                                // BTc2 [o][c]
        int r = idx - 704512, o = r / 384, c = r - o * 384;
        BTc2[r] = f2bf(cc2w[o * 384 + c]);
    }
}

// ---------------- CSR build ----------------

__global__ __launch_bounds__(256) void count_k(
    const int* __restrict__ dst, int* __restrict__ cnt)
{
    int e = blockIdx.x * 256 + threadIdx.x;
    atomicAdd(&cnt[dst[e]], 1);
}

// hierarchical scan: 32 blocks x 1024 local scan -> 1-wave block-sum scan
// -> 32 blocks offset add
__global__ __launch_bounds__(1024) void scan1_k(
    const int* __restrict__ cnt, int* __restrict__ rp, int* __restrict__ bsum)
{
    __shared__ int buf[1024];
    int b = blockIdx.x, tid = threadIdx.x;
    int n = (b << 10) + tid;
    int v = cnt[n];
    buf[tid] = v;
    __syncthreads();
    for (int off = 1; off < 1024; off <<= 1) {
        int x = (tid >= off) ? buf[tid - off] : 0;
        __syncthreads();
        buf[tid] += x;
        __syncthreads();
    }
    rp[n] = buf[tid] - v;                   // local exclusive
    if (tid == 1023) bsum[b] = buf[1023];   // block total
}

__global__ __launch_bounds__(64) void scan2_k(
    const int* __restrict__ bsum, int* __restrict__ boff, int* __restrict__ rp)
{
    int lane = threadIdx.x;
    int v = (lane < 32) ? bsum[lane] : 0;
    int s = v;
    #pragma unroll
    for (int off = 1; off < 32; off <<= 1) {
        int x = __shfl_up(s, off, 64);
        if (lane >= off) s += x;
    }
    if (lane < 32) boff[lane] = s - v;      // exclusive block offset
    if (lane == 31) rp[NNODE] = s;          // grand total
}

__global__ __launch_bounds__(1024) void scan3_k(
    int* __restrict__ rp, const int* __restrict__ boff)
{
    int b = blockIdx.x, tid = threadIdx.x;
    rp[(b << 10) + tid] += boff[b];
}

__global__ __launch_bounds__(256) void fill_k(
    const int* __restrict__ src, const int* __restrict__ dst,
    const int* __restrict__ et, const int* __restrict__ rp,
    int* __restrict__ pos, int* __restrict__ edat)
{
    int e = blockIdx.x * 256 + threadIdx.x;
    int d = dst[e];
    int p = atomicAdd(&pos[d], 1);
    edat[rp[d] + p] = src[e] | (et[e] << 20);
}

// ---------------- per-step kernels ----------------

// one wave per node: gather Hmsg[src, et*256 .. +256] rows, sum fp32 -> Aonly
// unrolled x8 so 8 gathers are in flight
__global__ __launch_bounds__(256) void agg2_k(
    const int* __restrict__ rp, const int* __restrict__ edat,
    const unsigned short* __restrict__ Hmsg, unsigned short* __restrict__ Aonly)
{
    int wave = threadIdx.x >> 6, lane = threadIdx.x & 63;
    int n = (blockIdx.x << 2) + wave;
    int e0 = rp[n], e1 = rp[n + 1];
    float a0 = 0.f, a1 = 0.f, a2 = 0.f, a3 = 0.f;
    const unsigned short* hc = Hmsg + (lane << 2);
    int e = e0;
    for (; e + 8 <= e1; e += 8) {
        u32x2 v[8];
        #pragma unroll
        for (int q = 0; q < 8; q++) {
            int d = edat[e + q];
            v[q] = *(const u32x2*)(hc + ((size_t)(d & 0xFFFFF) << 10) + ((d >> 20) << 8));
        }
        #pragma unroll
        for (int q = 0; q < 8; q++) {
            a0 += bf2f(v[q].x & 0xFFFFu); a1 += bf2f(v[q].x >> 16);
            a2 += bf2f(v[q].y & 0xFFFFu); a3 += bf2f(v[q].y >> 16);
        }
    }
    for (; e < e1; e++) {
        int d = edat[e];
        u32x2 v = *(const u32x2*)(hc + ((size_t)(d & 0xFFFFF) << 10) + ((d >> 20) << 8));
        a0 += bf2f(v.x & 0xFFFFu); a1 += bf2f(v.x >> 16);
        a2 += bf2f(v.y & 0xFFFFu); a3 += bf2f(v.y >> 16);
    }
    u32x2 p; p.x = pk2(a0, a1); p.y = pk2(a2, a3);
    *(u32x2*)(Aonly + (size_t)n * 256 + (lane << 2)) = p;
}

// ---- BK=64 staging helpers: tile stored as two stacked 32-K halves so
// global_load_lds lane-contiguity holds and ds_read pattern matches BK=32.
// Thread issues 4 gld16; chunk c = wave + p*4; half = c>>3.
#define STAGE_COORDS                                            \
    int srow[4], scb[4], soff[4];                               \
    _Pragma("unroll")                                           \
    for (int p = 0; p < 4; p++) {                               \
        int c = wave + p * 4;                                   \
        int half = c >> 3, cc = c & 7;                          \
        srow[p] = cc * 16 + (lane >> 2);                        \
        scb[p] = ((lane & 3) + half * 4) * 8;                   \
        soff[p] = half * 4096 + cc * 512;                       \
    }

// MFMA over one 64-K LDS tile pair (two 32-K halves), swapped operands
#define MFMA64(AS, BS)                                                        \
    _Pragma("unroll")                                                         \
    for (int h = 0; h < 2; h++) {                                             \
        bf16x8 af[4], bfr[4];                                                 \
        _Pragma("unroll")                                                     \
        for (int i = 0; i < 4; i++)                                           \
            af[i] = *(const bf16x8*)(&AS[h * 4096 + (qm + i * 16 + fm) * 32 + fkv * 8]); \
        _Pragma("unroll")                                                     \
        for (int i = 0; i < 4; i++)                                           \
            bfr[i] = *(const bf16x8*)(&BS[h * 4096 + (qn + i * 16 + fm) * 32 + fkv * 8]); \
        _Pragma("unroll")                                                     \
        for (int i = 0; i < 4; i++)                                           \
            _Pragma("unroll")                                                 \
            for (int j = 0; j < 4; j++)                                       \
                acc[i][j] = __builtin_amdgcn_mfma_f32_16x16x32_bf16(bfr[j], af[i], acc[i][j], 0, 0, 0); \
    }

// bf16 GEMM, B pre-transposed [N,K]; 128x128 tile, BK=64, 4 waves,
// global_load_lds staging, swapped MFMA (lane holds 4 consecutive N elems).
__global__ __launch_bounds__(256) void gemm_bt(
    const unsigned short* __restrict__ A, int lda,
    const unsigned short* __restrict__ Bt,
    unsigned short* __restrict__ Cb, int ldcb,
    const float* __restrict__ bias,
    int N, int K, int swz, int relu)
{
    __shared__ __align__(16) unsigned short As[128 * 64];
    __shared__ __align__(16) unsigned short Bs[128 * 64];
    const int tid = threadIdx.x;
    int id = blockIdx.x;
    if (swz) { int per = gridDim.x >> 3; id = (id & 7) * per + (id >> 3); }
    const int nb = N >> 7;
    const int bm = id / nb, bn = id - bm * nb;
    const int wave = tid >> 6, lane = tid & 63;
    const unsigned short* Ag = A + (size_t)(bm * 128) * lda;
    const unsigned short* Bg = Bt + (size_t)(bn * 128) * K;
    const int qm = (wave & 1) << 6, qn = (wave >> 1) << 6;
    const int fm = lane & 15, fkv = lane >> 4;
    STAGE_COORDS

    f32x4 acc[4][4] = {};

    for (int kb = 0; kb < K; kb += 64) {
        __syncthreads();
        #pragma unroll
        for (int p = 0; p < 4; p++)
            gld16(Ag + (size_t)srow[p] * lda + kb + scb[p], As + soff[p]);
        #pragma unroll
        for (int p = 0; p < 4; p++)
            gld16(Bg + (size_t)srow[p] * K + kb + scb[p], Bs + soff[p]);
        __syncthreads();
        MFMA64(As, Bs)
    }

    const int m0 = bm * 128 + qm + fm;
    const int n0 = bn * 128 + qn + (fkv << 2);
    #pragma unroll
    for (int i = 0; i < 4; i++) {
        int row = m0 + i * 16;
        #pragma unroll
        for (int j = 0; j < 4; j++) {
            int col = n0 + j * 16;
            float v0 = acc[i][j][0], v1 = acc[i][j][1],
                  v2 = acc[i][j][2], v3 = acc[i][j][3];
            if (bias) {
                float4 bv = *(const float4*)(bias + col);
                v0 += bv.x; v1 += bv.y; v2 += bv.z; v3 += bv.w;
            }
            if (relu) {
                v0 = fmaxf(v0, 0.f); v1 = fmaxf(v1, 0.f);
                v2 = fmaxf(v2, 0.f); v3 = fmaxf(v3, 0.f);
            }
            u32x2 p; p.x = pk2(v0, v1); p.y = pk2(v2, v3);
            *(u32x2*)(Cb + (size_t)row * ldcb + col) = p;
        }
    }
}

// conv1 as single K-extended GEMM: C[l,:] = relu(sum_k A[l+k,:] @ Wk + b)
// K layout: kb<768 -> h chunks (lda 256, shift kb>>8), kb>=768 -> f chunks
// (lda 128, shift (kb-768)>>7). BK=64 (divides both 256 and 128 chunks).
__global__ __launch_bounds__(256) void gemm_conv(
    const unsigned short* __restrict__ Ah,
    const unsigned short* __restrict__ Af,
    const unsigned short* __restrict__ Bt,
    unsigned short* __restrict__ Cb, int ldcb,
    const float* __restrict__ bias,
    int N, int K)
{
    __shared__ __align__(16) unsigned short As[128 * 64];
    __shared__ __align__(16) unsigned short Bs[128 * 64];
    const int tid = threadIdx.x;
    int id = blockIdx.x;
    { int per = gridDim.x >> 3; id = (id & 7) * per + (id >> 3); }
    const int nb = N >> 7;
    const int bm = id / nb, bn = id - bm * nb;
    const int wave = tid >> 6, lane = tid & 63;
    const unsigned short* Bg = Bt + (size_t)(bn * 128) * K;
    const int qm = (wave & 1) << 6, qn = (wave >> 1) << 6;
    const int fm = lane & 15, fkv = lane >> 4;
    STAGE_COORDS

    f32x4 acc[4][4] = {};

    for (int kb = 0; kb < K; kb += 64) {
        const unsigned short* base; int ldA, col, shift;
        if (kb < 768) { base = Ah; ldA = 256; shift = kb >> 8; col = kb & 255; }
        else { int r = kb - 768; base = Af; ldA = 128; shift = r >> 7; col = r & 127; }
        const unsigned short* Ag = base + (size_t)(bm * 128 + shift) * ldA + col;
        __syncthreads();
        #pragma unroll
        for (int p = 0; p < 4; p++)
            gld16(Ag + (size_t)srow[p] * ldA + scb[p], As + soff[p]);
        #pragma unroll
        for (int p = 0; p < 4; p++)
            gld16(Bg + (size_t)srow[p] * K + kb + scb[p], Bs + soff[p]);
        __syncthreads();
        MFMA64(As, Bs)
    }

    const int m0 = bm * 128 + qm + fm;
    const int n0 = bn * 128 + qn + (fkv << 2);
    #pragma unroll
    for (int i = 0; i < 4; i++) {
        int row = m0 + i * 16;
        #pragma unroll
        for (int j = 0; j < 4; j++) {
            int col = n0 + j * 16;
            float4 bv = *(const float4*)(bias + col);
            float v0 = fmaxf(acc[i][j][0] + bv.x, 0.f);
            float v1 = fmaxf(acc[i][j][1] + bv.y, 0.f);
            float v2 = fmaxf(acc[i][j][2] + bv.z, 0.f);
            float v3 = fmaxf(acc[i][j][3] + bv.w, 0.f);
            u32x2 p; p.x = pk2(v0, v1); p.y = pk2(v2, v3);
            *(u32x2*)(Cb + (size_t)row * ldcb + col) = p;
        }
    }
}

// GRU GEMM + fused gate epilogue (swapped MFMA, BK=64, fully unrolled K=512).
// A = [a|h] from Aonly / hbc (both [Nn,256] bf16); Bt [1024,512]
// gate-interleaved. gate g = j-frag, channel = band*16 + fkv*4 + r.
__global__ __launch_bounds__(256) void gemm_gru(
    const unsigned short* __restrict__ Aonly,
    const unsigned short* __restrict__ hbc,
    const unsigned short* __restrict__ Bt,
    const float* __restrict__ b2p,
    unsigned short* __restrict__ hbn)
{
    __shared__ __align__(16) unsigned short As[128 * 64];
    __shared__ __align__(16) unsigned short Bs[128 * 64];
    const int tid = threadIdx.x;
    int id = blockIdx.x;                        // 2048
    { int per = gridDim.x >> 3; id = (id & 7) * per + (id >> 3); }
    const int bm = id >> 3;
    const int bn = id & 7;
    const int wave = tid >> 6, lane = tid & 63;
    const unsigned short* Bg = Bt + (size_t)(bn * 128) * 512;
    const int qm = (wave & 1) << 6, qn = (wave >> 1) << 6;
    const int fm = lane & 15, fkv = lane >> 4;
    STAGE_COORDS

    f32x4 acc[4][4] = {};

    #pragma unroll
    for (int kb = 0; kb < 512; kb += 64) {
        const unsigned short* base = (kb < 256) ? Aonly : hbc;
        const unsigned short* Ag = base + (size_t)(bm * 128) * 256 + (kb & 255);
        __syncthreads();
        #pragma unroll
        for (int p = 0; p < 4; p++)
            gld16(Ag + (size_t)srow[p] * 256 + scb[p], As + soff[p]);
        #pragma unroll
        for (int p = 0; p < 4; p++)
            gld16(Bg + (size_t)srow[p] * 512 + kb + scb[p], Bs + soff[p]);
        __syncthreads();
        MFMA64(As, Bs)
    }

    // fused GRU gate epilogue (bf16 state, 8B vector I/O)
    const int band = (bn << 1) + (qn >> 6);
    const int chb = (band << 4) + (fkv << 2);
    const float4 brv = *(const float4*)(b2p + (band << 6) + 0  + (fkv << 2));
    const float4 bzv = *(const float4*)(b2p + (band << 6) + 16 + (fkv << 2));
    const float4 bgv = *(const float4*)(b2p + (band << 6) + 32 + (fkv << 2));
    const float4 bhv = *(const float4*)(b2p + (band << 6) + 48 + (fkv << 2));
    const float br_[4] = {brv.x, brv.y, brv.z, brv.w};
    const float bz_[4] = {bzv.x, bzv.y, bzv.z, bzv.w};
    const float bg_[4] = {bgv.x, bgv.y, bgv.z, bgv.w};
    const float bh_[4] = {bhv.x, bhv.y, bhv.z, bhv.w};
    const int m0 = bm * 128 + qm + fm;
    #pragma unroll
    for (int i = 0; i < 4; i++) {
        int row = m0 + i * 16;
        u32x2 hv = *(const u32x2*)(hbc + (size_t)row * 256 + chb);
        float hp[4] = {bf2f(hv.x & 0xFFFFu), bf2f(hv.x >> 16),
                       bf2f(hv.y & 0xFFFFu), bf2f(hv.y >> 16)};
        float hn[4];
        #pragma unroll
        for (int r = 0; r < 4; r++) {
            float rg = sigf(acc[i][0][r] + br_[r]);
            float zz = sigf(acc[i][1][r] + bz_[r]);
            float pre = acc[i][2][r] + bg_[r] + rg * (acc[i][3][r] + bh_[r]);
            pre = fminf(fmaxf(pre, -15.f), 15.f);
            float t = __expf(2.f * pre);
            float gq = (t - 1.f) / (t + 1.f);
            hn[r] = (1.f - zz) * gq + zz * hp[r];
        }
        u32x2 p; p.x = pk2(hn[0], hn[1]); p.y = pk2(hn[2], hn[3]);
        *(u32x2*)(hbn + (size_t)row * 256 + chb) = p;
    }
}

// maxpool over l (window 3, stride 2), bf16 input (relu pre-applied)
__global__ __launch_bounds__(256) void pool_k(
    const unsigned short* __restrict__ in, int ldin, int Lb_in, int L_out,
    int win, int C,
    unsigned short* __restrict__ ob, int ldo)
{
    int idx = blockIdx.x * 256 + threadIdx.x;
    int c = idx % C;
    int row = idx / C;
    int b = row / L_out, lp = row - b * L_out;
    const unsigned short* p = in + (size_t)(b * Lb_in + 2 * lp) * ldin + c;
    float m = bf2f(p[0]);
    for (int d = 1; d < win; d++) m = fmaxf(m, bf2f(p[(size_t)d * ldin]));
    ob[(size_t)row * ldo + c] = f2bf(m);
}

// fused pool2(win=2) + dot + mean + sigmoid.
// CY [128*126,256] bf16 (relu'd conv2-Y out), CZ [128*126,384] bf16
__global__ __launch_bounds__(64) void final_k(
    const unsigned short* __restrict__ CY, const unsigned short* __restrict__ CZ,
    const float* __restrict__ wy, const float* __restrict__ by,
    const float* __restrict__ wz, const float* __restrict__ bz,
    float* __restrict__ out)
{
    int b = blockIdx.x, lane = threadIdx.x;
    float val = 0.f;
    if (lane < 63) {
        const unsigned short* y0 = CY + (size_t)(b * 126 + 2 * lane) * 256;
        const unsigned short* y1 = y0 + 256;
        float y = 0.f;
        for (int o = 0; o < 256; o++)
            y += fmaxf(bf2f(y0[o]), bf2f(y1[o])) * wy[o];
        y += by[0];
        const unsigned short* z0 = CZ + (size_t)(b * 126 + 2 * lane) * 384;
        const unsigned short* z1 = z0 + 384;
        float z = 0.f;
        for (int o = 0; o < 384; o++)
            z += fmaxf(bf2f(z0[o]), bf2f(z1[o])) * wz[o];
        z += bz[0];
        val = y * z;
    }
    for (int off = 32; off > 0; off >>= 1) val += __shfl_down(val, off, 64);
    if (lane == 0) out[b] = sigf(val * (1.f / 63.f));
}

// ---------------- launch ----------------

extern "C" void kernel_launch(void* const* d_in, const int* in_sizes, int n_in,
                              void* d_out, int out_size, void* d_ws, size_t ws_size,
                              hipStream_t stream)
{
    const float* feat = (const float*)d_in[0];
    const int* src = (const int*)d_in[1];
    const int* dst = (const int*)d_in[2];
    const int* et  = (const int*)d_in[3];
    const float* Wm  = (const float*)d_in[4];
    const float* bm  = (const float*)d_in[5];
    const float* Wi  = (const float*)d_in[6];
    const float* Wh  = (const float*)d_in[7];
    const float* bi  = (const float*)d_in[8];
    const float* bh  = (const float*)d_in[9];
    const float* c1w = (const float*)d_in[10];
    const float* c1b = (const float*)d_in[11];
    const float* c2w = (const float*)d_in[12];
    const float* c2b = (const float*)d_in[13];
    const float* cc1w = (const float*)d_in[14];
    const float* cc1b = (const float*)d_in[15];
    const float* cc2w = (const float*)d_in[16];
    const float* cc2b = (const float*)d_in[17];
    const float* wy = (const float*)d_in[18];
    const float* by = (const float*)d_in[19];
    const float* wz = (const float*)d_in[20];
    const float* bz = (const float*)d_in[21];
    float* out = (float*)d_out;

    char* w = (char*)d_ws;
    size_t off = 0;
    auto alloc = [&](size_t bytes) -> char* {
        char* p = w + off; off += (bytes + 255) & ~(size_t)255; return p;
    };
    unsigned short* hb0 = (unsigned short*)alloc((size_t)(NNODE + 8) * 256 * 2);
    unsigned short* hb1 = (unsigned short*)alloc((size_t)(NNODE + 8) * 256 * 2);
    unsigned short* fb  = (unsigned short*)alloc((size_t)(NNODE + 8) * 128 * 2);
    unsigned short* Aonly = (unsigned short*)alloc((size_t)NNODE * 256 * 2);
    char* R = alloc((size_t)NNODE * 1024 * 2);          // Hmsg / conv1-out overlay
    unsigned short* Hmsg = (unsigned short*)R;          // [Nn,1024] bf16
    unsigned short* CbY  = (unsigned short*)R;          // [Nn,256] bf16 (conv1 Y)
    unsigned short* CbZ  = (unsigned short*)(R + (size_t)NNODE * 256 * 2); // [Nn,384]
    unsigned short* P    = (unsigned short*)alloc((size_t)16128 * 384 * 2);
    unsigned short* Cb2Y = (unsigned short*)alloc((size_t)16128 * 256 * 2);
    unsigned short* Cb2Z = (unsigned short*)alloc((size_t)16128 * 384 * 2);
    unsigned short* WT   = (unsigned short*)alloc(1024 * 256 * 2);
    unsigned short* B2T  = (unsigned short*)alloc(1024 * 512 * 2);
    float* b2            = (float*)alloc(1024 * 4);
    unsigned short* BTY  = (unsigned short*)alloc(256 * 768 * 2);
    unsigned short* BT2  = (unsigned short*)alloc(256 * 256 * 2);
    unsigned short* BTZ  = (unsigned short*)alloc(384 * 1152 * 2);
    unsigned short* BTc2 = (unsigned short*)alloc(384 * 384 * 2);
    int* rp     = (int*)alloc((NNODE + 1) * 4);
    int* pos    = (int*)alloc(NNODE * 4);
    int* cnt    = (int*)alloc(NNODE * 4);
    int* bsum   = (int*)alloc(32 * 4);
    int* boff   = (int*)alloc(32 * 4);
    int* edat   = (int*)alloc(NEDGE * 4);

    // setup
    hipLaunchKernelGGL(init_k, dim3(NNODE + 8), dim3(256), 0, stream, feat, hb0, hb1, fb);
    hipLaunchKernelGGL(prep_wmsg_k, dim3(1024), dim3(256), 0, stream, Wm, WT);
    hipLaunchKernelGGL(prep_gru_k, dim3(2048), dim3(256), 0, stream, Wi, Wh, B2T);
    hipLaunchKernelGGL(prep_bias2_k, dim3(4), dim3(256), 0, stream, bi, bh, b2);
    hipLaunchKernelGGL(prep_conv_k, dim3(3328), dim3(256), 0, stream,
                       c1w, c2w, cc1w, cc2w, BTY, BT2, BTZ, BTc2);
    hipMemsetAsync(pos, 0, NNODE * 4, stream);
    hipMemsetAsync(cnt, 0, NNODE * 4, stream);
    hipLaunchKernelGGL(count_k, dim3(NEDGE / 256), dim3(256), 0, stream, dst, cnt);
    hipLaunchKernelGGL(scan1_k, dim3(32), dim3(1024), 0, stream, cnt, rp, bsum);
    hipLaunchKernelGGL(scan2_k, dim3(1), dim3(64), 0, stream, bsum, boff, rp);
    hipLaunchKernelGGL(scan3_k, dim3(32), dim3(1024), 0, stream, rp, boff);
    hipLaunchKernelGGL(fill_k, dim3(NEDGE / 256), dim3(256), 0, stream, src, dst, et, rp, pos, edat);

    // 8 GGNN steps; bf16 state double-buffered (hb0 -> hb1 -> hb0 ...)
    // per step: Hmsg = hb@WT + bm  ->  Aonly[dst] = sum Hmsg[src, et]  ->  GRU
    unsigned short* hbuf[2] = {hb0, hb1};
    for (int step = 0; step < 8; step++) {
        unsigned short* cur = hbuf[step & 1];
        unsigned short* nxt = hbuf[(step + 1) & 1];
        hipLaunchKernelGGL(gemm_bt, dim3(2048), dim3(256), 0, stream,
            cur, 256, WT, Hmsg, 1024, bm, 1024, 256, 1, 0);
        hipLaunchKernelGGL(agg2_k, dim3(NNODE / 4), dim3(256), 0, stream, rp, edat, Hmsg, Aonly);
        hipLaunchKernelGGL(gemm_gru, dim3(2048), dim3(256), 0, stream,
            Aonly, cur, B2T, b2, nxt);
    }
    // final state is in hb0 (after 8 flips)

    // readout: Y path (relu fused in GEMMs, bf16 intermediates)
    hipLaunchKernelGGL(gemm_conv, dim3(512), dim3(256), 0, stream,
        hb0, (const unsigned short*)nullptr, BTY, CbY, 256, c1b, 256, 768);
    hipLaunchKernelGGL(pool_k, dim3(16128), dim3(256), 0, stream,
        CbY, 256, 256, 126, 3, 256, P, 256);
    hipLaunchKernelGGL(gemm_bt, dim3(252), dim3(256), 0, stream,
        P, 256, BT2, Cb2Y, 256, c2b, 256, 256, 0, 1);

    // Z path
    hipLaunchKernelGGL(gemm_conv, dim3(768), dim3(256), 0, stream,
        hb0, fb, BTZ, CbZ, 384, cc1b, 384, 1152);
    hipLaunchKernelGGL(pool_k, dim3(24192), dim3(256), 0, stream,
        CbZ, 384, 256, 126, 3, 384, P, 384);
    hipLaunchKernelGGL(gemm_bt, dim3(378), dim3(256), 0, stream,
        P, 384, BTc2, Cb2Z, 384, cc2b, 384, 384, 0, 1);

    // fused pool2 + readout heads
    hipLaunchKernelGGL(final_k, dim3(128), dim3(64), 0, stream,
        Cb2Y, Cb2Z, wy, by, wz, bz, out);
}

// Round 11
// 1315.150 us; speedup vs baseline: 1.3041x; 1.0163x over previous
//
#include <hip/hip_runtime.h>

#define DEV static __device__ __forceinline__

typedef float f32x4 __attribute__((ext_vector_type(4)));
typedef __bf16 bf16x8 __attribute__((ext_vector_type(8)));
typedef unsigned int u32x4 __attribute__((ext_vector_type(4)));
typedef unsigned int u32x2 __attribute__((ext_vector_type(2)));

#define NNODE 32768
#define NEDGE 393216

DEV unsigned short f2bf(float f) {
    unsigned int u = __builtin_bit_cast(unsigned int, f);
    u += 0x7FFFu + ((u >> 16) & 1u);
    return (unsigned short)(u >> 16);
}
DEV float bf2f(unsigned int b) {
    unsigned int u = b << 16;
    return __builtin_bit_cast(float, u);
}
DEV unsigned int pk2(float a, float b) {
    return (unsigned int)f2bf(a) | ((unsigned int)f2bf(b) << 16);
}
DEV float sigf(float x) { return 1.f / (1.f + __expf(-x)); }

// async global->LDS, 16B per lane; LDS dest = wave-uniform base + lane*16
DEV void gld16(const void* g, void* l) {
    __builtin_amdgcn_global_load_lds(
        (const __attribute__((address_space(1))) void*)(g),
        (__attribute__((address_space(3))) void*)(l),
        16, 0, 0);
}

// ---------------- setup kernels ----------------

__global__ __launch_bounds__(256) void init_k(
    const float* __restrict__ feat,
    unsigned short* __restrict__ hb0, unsigned short* __restrict__ hb1,
    unsigned short* __restrict__ fb)
{
    int idx = blockIdx.x * 256 + threadIdx.x;   // (NNODE+8)*256
    int r = idx >> 8, c = idx & 255;
    float f = 0.f;
    if (r < NNODE && c < 128) f = feat[(size_t)r * 128 + c];
    unsigned short v = f2bf(f);
    hb0[(size_t)r * 256 + c] = v;
    hb1[(size_t)r * 256 + c] = v;
    if (c < 128) fb[(size_t)r * 128 + c] = v;
}

// WT [1024,256]: row j = t*256+o, col d -> Wm[t][d][o]
__global__ __launch_bounds__(256) void prep_wmsg_k(
    const float* __restrict__ Wm, unsigned short* __restrict__ WT)
{
    int idx = blockIdx.x * 256 + threadIdx.x;   // 1024*256
    int j = idx >> 8, d = idx & 255;
    int t = j >> 8, o = j & 255;
    WT[idx] = f2bf(Wm[t * 65536 + d * 256 + o]);
}

// GRU weights gate-interleaved: col' = band*64 + g*16 + ch_low,
// ch = band*16 + ch_low, g in {0:r, 1:z, 2:ig, 3:hg}. K: k<256 -> a, else h.
__global__ __launch_bounds__(256) void prep_gru_k(
    const float* __restrict__ Wi, const float* __restrict__ Wh,
    unsigned short* __restrict__ B2T)
{
    int idx = blockIdx.x * 256 + threadIdx.x;   // 1024*512
    int j = idx >> 9, k = idx & 511;
    int band = j >> 6, g = (j >> 4) & 3, ch = (band << 4) + (j & 15);
    float v = 0.f;
    if (g == 0) v = (k < 256) ? Wi[k * 768 + ch] : Wh[(k - 256) * 768 + ch];
    else if (g == 1) v = (k < 256) ? Wi[k * 768 + 256 + ch] : Wh[(k - 256) * 768 + 256 + ch];
    else if (g == 2) { if (k < 256) v = Wi[k * 768 + 512 + ch]; }
    else { if (k >= 256) v = Wh[(k - 256) * 768 + 512 + ch]; }
    B2T[idx] = f2bf(v);
}

__global__ __launch_bounds__(256) void prep_bias2_k(
    const float* __restrict__ bi, const float* __restrict__ bh,
    float* __restrict__ b2)
{
    int j = blockIdx.x * 256 + threadIdx.x;     // 1024
    int band = j >> 6, g = (j >> 4) & 3, ch = (band << 4) + (j & 15);
    float v;
    if (g == 0) v = bi[ch] + bh[ch];
    else if (g == 1) v = bi[256 + ch] + bh[256 + ch];
    else if (g == 2) v = bi[512 + ch];
    else v = bh[512 + ch];
    b2[j] = v;
}

// pack conv weights: BTY [256][768] (kk=k*256+c), BT2 [256][256],
// BTZ [384][1152] (h chunks then f chunks), BTc2 [384][384]
__global__ __launch_bounds__(256) void prep_conv_k(
    const float* __restrict__ c1w, const float* __restrict__ c2w,
    const float* __restrict__ cc1w, const float* __restrict__ cc2w,
    unsigned short* __restrict__ BTY, unsigned short* __restrict__ BT2,
    unsigned short* __restrict__ BTZ, unsigned short* __restrict__ BTc2)
{
    int idx = blockIdx.x * 256 + threadIdx.x;   // 851968 total
    if (idx < 196608) {                                     // BTY
        int o = idx / 768, kk = idx - o * 768, k = kk >> 8, c = kk & 255;
        BTY[idx] = f2bf(c1w[o * 768 + c * 3 + k]);
    } else if (idx < 262144) {                              // BT2 [o][c]
        int r = idx - 196608, o = r >> 8, c = r & 255;
        BT2[r] = f2bf(c2w[o * 256 + c]);
    } else if (idx < 704512) {                              // BTZ
        int jx = idx - 262144, o = jx / 1152, kk = jx - o * 1152;
        float v;
        if (kk < 768) { int k = kk >> 8, c = kk & 255; v = cc1w[o * 1152 + c * 3 + k]; }
        else { int r = kk - 768, kf = r >> 7, cf = r & 127; v = cc1w[o * 1152 + (256 + cf) * 3 + kf]; }
        BTZ[jx] = f2bf(v);
    } else {                                                // BTc2 [o][c]
        int r = idx - 704512, o = r / 384, c = r - o * 384;
        BTc2[r] = f2bf(cc2w[o * 384 + c]);
    }
}

// ---------------- CSR build ----------------

__global__ __launch_bounds__(256) void count_k(
    const int* __restrict__ dst, int* __restrict__ cnt)
{
    int e = blockIdx.x * 256 + threadIdx.x;
    atomicAdd(&cnt[dst[e]], 1);
}

// hierarchical scan: 32 blocks x 1024 local scan -> 1-wave block-sum scan
// -> 32 blocks offset add
__global__ __launch_bounds__(1024) void scan1_k(
    const int* __restrict__ cnt, int* __restrict__ rp, int* __restrict__ bsum)
{
    __shared__ int buf[1024];
    int b = blockIdx.x, tid = threadIdx.x;
    int n = (b << 10) + tid;
    int v = cnt[n];
    buf[tid] = v;
    __syncthreads();
    for (int off = 1; off < 1024; off <<= 1) {
        int x = (tid >= off) ? buf[tid - off] : 0;
        __syncthreads();
        buf[tid] += x;
        __syncthreads();
    }
    rp[n] = buf[tid] - v;                   // local exclusive
    if (tid == 1023) bsum[b] = buf[1023];   // block total
}

__global__ __launch_bounds__(64) void scan2_k(
    const int* __restrict__ bsum, int* __restrict__ boff, int* __restrict__ rp)
{
    int lane = threadIdx.x;
    int v = (lane < 32) ? bsum[lane] : 0;
    int s = v;
    #pragma unroll
    for (int off = 1; off < 32; off <<= 1) {
        int x = __shfl_up(s, off, 64);
        if (lane >= off) s += x;
    }
    if (lane < 32) boff[lane] = s - v;      // exclusive block offset
    if (lane == 31) rp[NNODE] = s;          // grand total
}

__global__ __launch_bounds__(1024) void scan3_k(
    int* __restrict__ rp, const int* __restrict__ boff)
{
    int b = blockIdx.x, tid = threadIdx.x;
    rp[(b << 10) + tid] += boff[b];
}

__global__ __launch_bounds__(256) void fill_k(
    const int* __restrict__ src, const int* __restrict__ dst,
    const int* __restrict__ et, const int* __restrict__ rp,
    int* __restrict__ pos, int* __restrict__ edat)
{
    int e = blockIdx.x * 256 + threadIdx.x;
    int d = dst[e];
    int p = atomicAdd(&pos[d], 1);
    edat[rp[d] + p] = src[e] | (et[e] << 20);
}

// ---------------- per-step kernels ----------------

// one wave per node: gather Hmsg[src, et*256 .. +256] rows, sum fp32 -> Aonly
// unrolled x8 so 8 gathers are in flight
__global__ __launch_bounds__(256) void agg2_k(
    const int* __restrict__ rp, const int* __restrict__ edat,
    const unsigned short* __restrict__ Hmsg, unsigned short* __restrict__ Aonly)
{
    int wave = threadIdx.x >> 6, lane = threadIdx.x & 63;
    int n = (blockIdx.x << 2) + wave;
    int e0 = rp[n], e1 = rp[n + 1];
    float a0 = 0.f, a1 = 0.f, a2 = 0.f, a3 = 0.f;
    const unsigned short* hc = Hmsg + (lane << 2);
    int e = e0;
    for (; e + 8 <= e1; e += 8) {
        u32x2 v[8];
        #pragma unroll
        for (int q = 0; q < 8; q++) {
            int d = edat[e + q];
            v[q] = *(const u32x2*)(hc + ((size_t)(d & 0xFFFFF) << 10) + ((d >> 20) << 8));
        }
        #pragma unroll
        for (int q = 0; q < 8; q++) {
            a0 += bf2f(v[q].x & 0xFFFFu); a1 += bf2f(v[q].x >> 16);
            a2 += bf2f(v[q].y & 0xFFFFu); a3 += bf2f(v[q].y >> 16);
        }
    }
    for (; e < e1; e++) {
        int d = edat[e];
        u32x2 v = *(const u32x2*)(hc + ((size_t)(d & 0xFFFFF) << 10) + ((d >> 20) << 8));
        a0 += bf2f(v.x & 0xFFFFu); a1 += bf2f(v.x >> 16);
        a2 += bf2f(v.y & 0xFFFFu); a3 += bf2f(v.y >> 16);
    }
    u32x2 p; p.x = pk2(a0, a1); p.y = pk2(a2, a3);
    *(u32x2*)(Aonly + (size_t)n * 256 + (lane << 2)) = p;
}

// ---- BK=64 staging helpers, bank-conflict-free XOR swizzle.
// LDS tile = two stacked 32-K halves; within a half, row r's 4 chunks of
// 8 bf16 are stored PERMUTED: global chunk c sits at position c ^ s(r),
// s(r) = (r>>1)&3. Staging lane l (writes LDS base+l*16) therefore fetches
// global chunk (l&3) ^ ((l>>3)&3)  [since s(row(l)) = (l>>3)&3].
// Readers fetch chunk fkv from position fkv ^ ((fm>>1)&3) — this spreads
// each 8-lane LDS phase across all 8 bank-quads (was 2) -> conflict-free.
#define STAGE_COORDS                                            \
    int srow[4], scb[4], soff[4];                               \
    _Pragma("unroll")                                           \
    for (int p = 0; p < 4; p++) {                               \
        int c = wave + p * 4;                                   \
        int half = c >> 3, cc = c & 7;                          \
        srow[p] = cc * 16 + (lane >> 2);                        \
        scb[p] = (((lane & 3) ^ ((lane >> 3) & 3)) + half * 4) * 8; \
        soff[p] = half * 4096 + cc * 512;                       \
    }

// MFMA over one 64-K LDS tile pair (two 32-K halves), swapped operands,
// swizzled fragment reads
#define MFMA64(AS, BS)                                                        \
    _Pragma("unroll")                                                         \
    for (int h = 0; h < 2; h++) {                                             \
        bf16x8 af[4], bfr[4];                                                 \
        _Pragma("unroll")                                                     \
        for (int i = 0; i < 4; i++)                                           \
            af[i] = *(const bf16x8*)(&AS[h * 4096 + (qm + i * 16 + fm) * 32 + fksw * 8]); \
        _Pragma("unroll")                                                     \
        for (int i = 0; i < 4; i++)                                           \
            bfr[i] = *(const bf16x8*)(&BS[h * 4096 + (qn + i * 16 + fm) * 32 + fksw * 8]); \
        _Pragma("unroll")                                                     \
        for (int i = 0; i < 4; i++)                                           \
            _Pragma("unroll")                                                 \
            for (int j = 0; j < 4; j++)                                       \
                acc[i][j] = __builtin_amdgcn_mfma_f32_16x16x32_bf16(bfr[j], af[i], acc[i][j], 0, 0, 0); \
    }

// bf16 GEMM, B pre-transposed [N,K]; 128x128 tile, BK=64, 4 waves,
// global_load_lds staging, swapped MFMA (lane holds 4 consecutive N elems).
__global__ __launch_bounds__(256) void gemm_bt(
    const unsigned short* __restrict__ A, int lda,
    const unsigned short* __restrict__ Bt,
    unsigned short* __restrict__ Cb, int ldcb,
    const float* __restrict__ bias,
    int N, int K, int swz, int relu)
{
    __shared__ __align__(16) unsigned short As[128 * 64];
    __shared__ __align__(16) unsigned short Bs[128 * 64];
    const int tid = threadIdx.x;
    int id = blockIdx.x;
    if (swz) { int per = gridDim.x >> 3; id = (id & 7) * per + (id >> 3); }
    const int nb = N >> 7;
    const int bm = id / nb, bn = id - bm * nb;
    const int wave = tid >> 6, lane = tid & 63;
    const unsigned short* Ag = A + (size_t)(bm * 128) * lda;
    const unsigned short* Bg = Bt + (size_t)(bn * 128) * K;
    const int qm = (wave & 1) << 6, qn = (wave >> 1) << 6;
    const int fm = lane & 15, fkv = lane >> 4;
    const int fksw = fkv ^ ((fm >> 1) & 3);
    STAGE_COORDS

    f32x4 acc[4][4] = {};

    for (int kb = 0; kb < K; kb += 64) {
        __syncthreads();
        #pragma unroll
        for (int p = 0; p < 4; p++)
            gld16(Ag + (size_t)srow[p] * lda + kb + scb[p], As + soff[p]);
        #pragma unroll
        for (int p = 0; p < 4; p++)
            gld16(Bg + (size_t)srow[p] * K + kb + scb[p], Bs + soff[p]);
        __syncthreads();
        MFMA64(As, Bs)
    }

    const int m0 = bm * 128 + qm + fm;
    const int n0 = bn * 128 + qn + (fkv << 2);
    #pragma unroll
    for (int i = 0; i < 4; i++) {
        int row = m0 + i * 16;
        #pragma unroll
        for (int j = 0; j < 4; j++) {
            int col = n0 + j * 16;
            float v0 = acc[i][j][0], v1 = acc[i][j][1],
                  v2 = acc[i][j][2], v3 = acc[i][j][3];
            if (bias) {
                float4 bv = *(const float4*)(bias + col);
                v0 += bv.x; v1 += bv.y; v2 += bv.z; v3 += bv.w;
            }
            if (relu) {
                v0 = fmaxf(v0, 0.f); v1 = fmaxf(v1, 0.f);
                v2 = fmaxf(v2, 0.f); v3 = fmaxf(v3, 0.f);
            }
            u32x2 p; p.x = pk2(v0, v1); p.y = pk2(v2, v3);
            *(u32x2*)(Cb + (size_t)row * ldcb + col) = p;
        }
    }
}

// conv1 as single K-extended GEMM: C[l,:] = relu(sum_k A[l+k,:] @ Wk + b)
// K layout: kb<768 -> h chunks (lda 256, shift kb>>8), kb>=768 -> f chunks
// (lda 128, shift (kb-768)>>7). BK=64 (divides both 256 and 128 chunks).
__global__ __launch_bounds__(256) void gemm_conv(
    const unsigned short* __restrict__ Ah,
    const unsigned short* __restrict__ Af,
    const unsigned short* __restrict__ Bt,
    unsigned short* __restrict__ Cb, int ldcb,
    const float* __restrict__ bias,
    int N, int K)
{
    __shared__ __align__(16) unsigned short As[128 * 64];
    __shared__ __align__(16) unsigned short Bs[128 * 64];
    const int tid = threadIdx.x;
    int id = blockIdx.x;
    { int per = gridDim.x >> 3; id = (id & 7) * per + (id >> 3); }
    const int nb = N >> 7;
    const int bm = id / nb, bn = id - bm * nb;
    const int wave = tid >> 6, lane = tid & 63;
    const unsigned short* Bg = Bt + (size_t)(bn * 128) * K;
    const int qm = (wave & 1) << 6, qn = (wave >> 1) << 6;
    const int fm = lane & 15, fkv = lane >> 4;
    const int fksw = fkv ^ ((fm >> 1) & 3);
    STAGE_COORDS

    f32x4 acc[4][4] = {};

    for (int kb = 0; kb < K; kb += 64) {
        const unsigned short* base; int ldA, col, shift;
        if (kb < 768) { base = Ah; ldA = 256; shift = kb >> 8; col = kb & 255; }
        else { int r = kb - 768; base = Af; ldA = 128; shift = r >> 7; col = r & 127; }
        const unsigned short* Ag = base + (size_t)(bm * 128 + shift) * ldA + col;
        __syncthreads();
        #pragma unroll
        for (int p = 0; p < 4; p++)
            gld16(Ag + (size_t)srow[p] * ldA + scb[p], As + soff[p]);
        #pragma unroll
        for (int p = 0; p < 4; p++)
            gld16(Bg + (size_t)srow[p] * K + kb + scb[p], Bs + soff[p]);
        __syncthreads();
        MFMA64(As, Bs)
    }

    const int m0 = bm * 128 + qm + fm;
    const int n0 = bn * 128 + qn + (fkv << 2);
    #pragma unroll
    for (int i = 0; i < 4; i++) {
        int row = m0 + i * 16;
        #pragma unroll
        for (int j = 0; j < 4; j++) {
            int col = n0 + j * 16;
            float4 bv = *(const float4*)(bias + col);
            float v0 = fmaxf(acc[i][j][0] + bv.x, 0.f);
            float v1 = fmaxf(acc[i][j][1] + bv.y, 0.f);
            float v2 = fmaxf(acc[i][j][2] + bv.z, 0.f);
            float v3 = fmaxf(acc[i][j][3] + bv.w, 0.f);
            u32x2 p; p.x = pk2(v0, v1); p.y = pk2(v2, v3);
            *(u32x2*)(Cb + (size_t)row * ldcb + col) = p;
        }
    }
}

// GRU GEMM + fused gate epilogue (swapped MFMA, BK=64, fully unrolled K=512).
// A = [a|h] from Aonly / hbc (both [Nn,256] bf16); Bt [1024,512]
// gate-interleaved. gate g = j-frag, channel = band*16 + fkv*4 + r.
__global__ __launch_bounds__(256) void gemm_gru(
    const unsigned short* __restrict__ Aonly,
    const unsigned short* __restrict__ hbc,
    const unsigned short* __restrict__ Bt,
    const float* __restrict__ b2p,
    unsigned short* __restrict__ hbn)
{
    __shared__ __align__(16) unsigned short As[128 * 64];
    __shared__ __align__(16) unsigned short Bs[128 * 64];
    const int tid = threadIdx.x;
    int id = blockIdx.x;                        // 2048
    { int per = gridDim.x >> 3; id = (id & 7) * per + (id >> 3); }
    const int bm = id >> 3;
    const int bn = id & 7;
    const int wave = tid >> 6, lane = tid & 63;
    const unsigned short* Bg = Bt + (size_t)(bn * 128) * 512;
    const int qm = (wave & 1) << 6, qn = (wave >> 1) << 6;
    const int fm = lane & 15, fkv = lane >> 4;
    const int fksw = fkv ^ ((fm >> 1) & 3);
    STAGE_COORDS

    f32x4 acc[4][4] = {};

    #pragma unroll
    for (int kb = 0; kb < 512; kb += 64) {
        const unsigned short* base = (kb < 256) ? Aonly : hbc;
        const unsigned short* Ag = base + (size_t)(bm * 128) * 256 + (kb & 255);
        __syncthreads();
        #pragma unroll
        for (int p = 0; p < 4; p++)
            gld16(Ag + (size_t)srow[p] * 256 + scb[p], As + soff[p]);
        #pragma unroll
        for (int p = 0; p < 4; p++)
            gld16(Bg + (size_t)srow[p] * 512 + kb + scb[p], Bs + soff[p]);
        __syncthreads();
        MFMA64(As, Bs)
    }

    // fused GRU gate epilogue (bf16 state, 8B vector I/O)
    const int band = (bn << 1) + (qn >> 6);
    const int chb = (band << 4) + (fkv << 2);
    const float4 brv = *(const float4*)(b2p + (band << 6) + 0  + (fkv << 2));
    const float4 bzv = *(const float4*)(b2p + (band << 6) + 16 + (fkv << 2));
    const float4 bgv = *(const float4*)(b2p + (band << 6) + 32 + (fkv << 2));
    const float4 bhv = *(const float4*)(b2p + (band << 6) + 48 + (fkv << 2));
    const float br_[4] = {brv.x, brv.y, brv.z, brv.w};
    const float bz_[4] = {bzv.x, bzv.y, bzv.z, bzv.w};
    const float bg_[4] = {bgv.x, bgv.y, bgv.z, bgv.w};
    const float bh_[4] = {bhv.x, bhv.y, bhv.z, bhv.w};
    const int m0 = bm * 128 + qm + fm;
    #pragma unroll
    for (int i = 0; i < 4; i++) {
        int row = m0 + i * 16;
        u32x2 hv = *(const u32x2*)(hbc + (size_t)row * 256 + chb);
        float hp[4] = {bf2f(hv.x & 0xFFFFu), bf2f(hv.x >> 16),
                       bf2f(hv.y & 0xFFFFu), bf2f(hv.y >> 16)};
        float hn[4];
        #pragma unroll
        for (int r = 0; r < 4; r++) {
            float rg = sigf(acc[i][0][r] + br_[r]);
            float zz = sigf(acc[i][1][r] + bz_[r]);
            float pre = acc[i][2][r] + bg_[r] + rg * (acc[i][3][r] + bh_[r]);
            pre = fminf(fmaxf(pre, -15.f), 15.f);
            float t = __expf(2.f * pre);
            float gq = (t - 1.f) / (t + 1.f);
            hn[r] = (1.f - zz) * gq + zz * hp[r];
        }
        u32x2 p; p.x = pk2(hn[0], hn[1]); p.y = pk2(hn[2], hn[3]);
        *(u32x2*)(hbn + (size_t)row * 256 + chb) = p;
    }
}

// maxpool over l (window 3, stride 2), bf16 input (relu pre-applied)
__global__ __launch_bounds__(256) void pool_k(
    const unsigned short* __restrict__ in, int ldin, int Lb_in, int L_out,
    int win, int C,
    unsigned short* __restrict__ ob, int ldo)
{
    int idx = blockIdx.x * 256 + threadIdx.x;
    int c = idx % C;
    int row = idx / C;
    int b = row / L_out, lp = row - b * L_out;
    const unsigned short* p = in + (size_t)(b * Lb_in + 2 * lp) * ldin + c;
    float m = bf2f(p[0]);
    for (int d = 1; d < win; d++) m = fmaxf(m, bf2f(p[(size_t)d * ldin]));
    ob[(size_t)row * ldo + c] = f2bf(m);
}

// fused pool2(win=2) + dot + mean + sigmoid.
// CY [128*126,256] bf16 (relu'd conv2-Y out), CZ [128*126,384] bf16
__global__ __launch_bounds__(64) void final_k(
    const unsigned short* __restrict__ CY, const unsigned short* __restrict__ CZ,
    const float* __restrict__ wy, const float* __restrict__ by,
    const float* __restrict__ wz, const float* __restrict__ bz,
    float* __restrict__ out)
{
    int b = blockIdx.x, lane = threadIdx.x;
    float val = 0.f;
    if (lane < 63) {
        const unsigned short* y0 = CY + (size_t)(b * 126 + 2 * lane) * 256;
        const unsigned short* y1 = y0 + 256;
        float y = 0.f;
        for (int o = 0; o < 256; o++)
            y += fmaxf(bf2f(y0[o]), bf2f(y1[o])) * wy[o];
        y += by[0];
        const unsigned short* z0 = CZ + (size_t)(b * 126 + 2 * lane) * 384;
        const unsigned short* z1 = z0 + 384;
        float z = 0.f;
        for (int o = 0; o < 384; o++)
            z += fmaxf(bf2f(z0[o]), bf2f(z1[o])) * wz[o];
        z += bz[0];
        val = y * z;
    }
    for (int off = 32; off > 0; off >>= 1) val += __shfl_down(val, off, 64);
    if (lane == 0) out[b] = sigf(val * (1.f / 63.f));
}

// ---------------- launch ----------------

extern "C" void kernel_launch(void* const* d_in, const int* in_sizes, int n_in,
                              void* d_out, int out_size, void* d_ws, size_t ws_size,
                              hipStream_t stream)
{
    const float* feat = (const float*)d_in[0];
    const int* src = (const int*)d_in[1];
    const int* dst = (const int*)d_in[2];
    const int* et  = (const int*)d_in[3];
    const float* Wm  = (const float*)d_in[4];
    const float* bm  = (const float*)d_in[5];
    const float* Wi  = (const float*)d_in[6];
    const float* Wh  = (const float*)d_in[7];
    const float* bi  = (const float*)d_in[8];
    const float* bh  = (const float*)d_in[9];
    const float* c1w = (const float*)d_in[10];
    const float* c1b = (const float*)d_in[11];
    const float* c2w = (const float*)d_in[12];
    const float* c2b = (const float*)d_in[13];
    const float* cc1w = (const float*)d_in[14];
    const float* cc1b = (const float*)d_in[15];
    const float* cc2w = (const float*)d_in[16];
    const float* cc2b = (const float*)d_in[17];
    const float* wy = (const float*)d_in[18];
    const float* by = (const float*)d_in[19];
    const float* wz = (const float*)d_in[20];
    const float* bz = (const float*)d_in[21];
    float* out = (float*)d_out;

    char* w = (char*)d_ws;
    size_t off = 0;
    auto alloc = [&](size_t bytes) -> char* {
        char* p = w + off; off += (bytes + 255) & ~(size_t)255; return p;
    };
    unsigned short* hb0 = (unsigned short*)alloc((size_t)(NNODE + 8) * 256 * 2);
    unsigned short* hb1 = (unsigned short*)alloc((size_t)(NNODE + 8) * 256 * 2);
    unsigned short* fb  = (unsigned short*)alloc((size_t)(NNODE + 8) * 128 * 2);
    unsigned short* Aonly = (unsigned short*)alloc((size_t)NNODE * 256 * 2);
    char* R = alloc((size_t)NNODE * 1024 * 2);          // Hmsg / conv1-out overlay
    unsigned short* Hmsg = (unsigned short*)R;          // [Nn,1024] bf16
    unsigned short* CbY  = (unsigned short*)R;          // [Nn,256] bf16 (conv1 Y)
    unsigned short* CbZ  = (unsigned short*)(R + (size_t)NNODE * 256 * 2); // [Nn,384]
    unsigned short* P    = (unsigned short*)alloc((size_t)16128 * 384 * 2);
    unsigned short* Cb2Y = (unsigned short*)alloc((size_t)16128 * 256 * 2);
    unsigned short* Cb2Z = (unsigned short*)alloc((size_t)16128 * 384 * 2);
    unsigned short* WT   = (unsigned short*)alloc(1024 * 256 * 2);
    unsigned short* B2T  = (unsigned short*)alloc(1024 * 512 * 2);
    float* b2            = (float*)alloc(1024 * 4);
    unsigned short* BTY  = (unsigned short*)alloc(256 * 768 * 2);
    unsigned short* BT2  = (unsigned short*)alloc(256 * 256 * 2);
    unsigned short* BTZ  = (unsigned short*)alloc(384 * 1152 * 2);
    unsigned short* BTc2 = (unsigned short*)alloc(384 * 384 * 2);
    int* rp     = (int*)alloc((NNODE + 1) * 4);
    int* pos    = (int*)alloc(NNODE * 4);
    int* cnt    = (int*)alloc(NNODE * 4);
    int* bsum   = (int*)alloc(32 * 4);
    int* boff   = (int*)alloc(32 * 4);
    int* edat   = (int*)alloc(NEDGE * 4);

    // setup
    hipLaunchKernelGGL(init_k, dim3(NNODE + 8), dim3(256), 0, stream, feat, hb0, hb1, fb);
    hipLaunchKernelGGL(prep_wmsg_k, dim3(1024), dim3(256), 0, stream, Wm, WT);
    hipLaunchKernelGGL(prep_gru_k, dim3(2048), dim3(256), 0, stream, Wi, Wh, B2T);
    hipLaunchKernelGGL(prep_bias2_k, dim3(4), dim3(256), 0, stream, bi, bh, b2);
    hipLaunchKernelGGL(prep_conv_k, dim3(3328), dim3(256), 0, stream,
                       c1w, c2w, cc1w, cc2w, BTY, BT2, BTZ, BTc2);
    hipMemsetAsync(pos, 0, NNODE * 4, stream);
    hipMemsetAsync(cnt, 0, NNODE * 4, stream);
    hipLaunchKernelGGL(count_k, dim3(NEDGE / 256), dim3(256), 0, stream, dst, cnt);
    hipLaunchKernelGGL(scan1_k, dim3(32), dim3(1024), 0, stream, cnt, rp, bsum);
    hipLaunchKernelGGL(scan2_k, dim3(1), dim3(64), 0, stream, bsum, boff, rp);
    hipLaunchKernelGGL(scan3_k, dim3(32), dim3(1024), 0, stream, rp, boff);
    hipLaunchKernelGGL(fill_k, dim3(NEDGE / 256), dim3(256), 0, stream, src, dst, et, rp, pos, edat);

    // 8 GGNN steps; bf16 state double-buffered (hb0 -> hb1 -> hb0 ...)
    // per step: Hmsg = hb@WT + bm  ->  Aonly[dst] = sum Hmsg[src, et]  ->  GRU
    unsigned short* hbuf[2] = {hb0, hb1};
    for (int step = 0; step < 8; step++) {
        unsigned short* cur = hbuf[step & 1];
        unsigned short* nxt = hbuf[(step + 1) & 1];
        hipLaunchKernelGGL(gemm_bt, dim3(2048), dim3(256), 0, stream,
            cur, 256, WT, Hmsg, 1024, bm, 1024, 256, 1, 0);
        hipLaunchKernelGGL(agg2_k, dim3(NNODE / 4), dim3(256), 0, stream, rp, edat, Hmsg, Aonly);
        hipLaunchKernelGGL(gemm_gru, dim3(2048), dim3(256), 0, stream,
            Aonly, cur, B2T, b2, nxt);
    }
    // final state is in hb0 (after 8 flips)

    // readout: Y path (relu fused in GEMMs, bf16 intermediates)
    hipLaunchKernelGGL(gemm_conv, dim3(512), dim3(256), 0, stream,
        hb0, (const unsigned short*)nullptr, BTY, CbY, 256, c1b, 256, 768);
    hipLaunchKernelGGL(pool_k, dim3(16128), dim3(256), 0, stream,
        CbY, 256, 256, 126, 3, 256, P, 256);
    hipLaunchKernelGGL(gemm_bt, dim3(252), dim3(256), 0, stream,
        P, 256, BT2, Cb2Y, 256, c2b, 256, 256, 0, 1);

    // Z path
    hipLaunchKernelGGL(gemm_conv, dim3(768), dim3(256), 0, stream,
        hb0, fb, BTZ, CbZ, 384, cc1b, 384, 1152);
    hipLaunchKernelGGL(pool_k, dim3(24192), dim3(256), 0, stream,
        CbZ, 384, 256, 126, 3, 384, P, 384);
    hipLaunchKernelGGL(gemm_bt, dim3(378), dim3(256), 0, stream,
        P, 384, BTc2, Cb2Z, 384, cc2b, 384, 384, 0, 1);

    // fused pool2 + readout heads
    hipLaunchKernelGGL(final_k, dim3(128), dim3(64), 0, stream,
        Cb2Y, Cb2Z, wy, by, wz, bz, out);
}